// Round 12
// baseline (306.963 us; speedup 1.0000x reference)
//
#include <hip/hip_runtime.h>
#include <math.h>

// Problem constants (match reference)
#define NROWS 65536          // B*S = 16*4096
#define CIN   768
#define QCOUNT 524288.0      // NROWS * DDIM
#define RPW   8              // rows per wave (phase A: 4 pairs)
#define NBLK  (NROWS / (4 * RPW))   // 2048 blocks of 4 waves

// R12 = R11 (fused temporal-phase, 101.5us) + occupancy push:
// 3-buffer z rotation (A,B,C cycle over 4 pairs; depth-1 prefetch kept;
// -12 VGPR vs 4-buffer ping-pong) + launch_bounds(256,5) to pin VGPR=102
// -> 5 waves/SIMD (was 4 at VGPR=116). NOT an R4/R6-class cap: forced
// squeeze is ~2 rematerializable regs, not a 20+ live-array. Tripwire:
// FETCH_SIZE > 160MB or dur regression -> revert to R11.
// Decision path bit-identical to the verified absmax-0.0 kernels.

// Distributing butterfly: reduce 8 per-lane f64 partials across 64 lanes,
// delivering zc[d] to lanes with (lane&7)==d. Fixed order, static selects.
#define REDUCE_TO_MINE(da, out)                                            \
    {                                                                      \
        double k0 = b0 ? da[1] : da[0], s0 = b0 ? da[0] : da[1];           \
        double k1 = b0 ? da[3] : da[2], s1 = b0 ? da[2] : da[3];           \
        double k2 = b0 ? da[5] : da[4], s2 = b0 ? da[4] : da[5];           \
        double k3 = b0 ? da[7] : da[6], s3 = b0 ? da[6] : da[7];           \
        k0 += __shfl_xor(s0, 1); k1 += __shfl_xor(s1, 1);                  \
        k2 += __shfl_xor(s2, 1); k3 += __shfl_xor(s3, 1);                  \
        double m0 = b1 ? k1 : k0, t0 = b1 ? k0 : k1;                       \
        double m1 = b1 ? k3 : k2, t1 = b1 ? k2 : k3;                       \
        m0 += __shfl_xor(t0, 2); m1 += __shfl_xor(t1, 2);                  \
        double r = b2 ? m1 : m0, tq = b2 ? m0 : m1;                        \
        r += __shfl_xor(tq, 4);                                            \
        r += __shfl_xor(r, 8);                                             \
        r += __shfl_xor(r, 16);                                            \
        r += __shfl_xor(r, 32);                                            \
        out = r;                                                           \
    }

// Load one row's z (3 coalesced float4) + u (coalesced permuted 256B)
#define LOADZ(B, row)                                                      \
    B##0 = z4[(size_t)(row) * 192 + lane];                                 \
    B##1 = z4[(size_t)(row) * 192 + lane + 64];                           \
    B##2 = z4[(size_t)(row) * 192 + lane + 128];                          \
    B##u = u[(size_t)(row) * 64 + dg * 8 + lev];

// compress TWO rows (buffers P,Q) sharing each Wc LDS read. Per-row
// arithmetic is the EXACT order of the verified absmax-0.0 kernel.
#define COMPRESS2(P, Q, ZCA, ZCB)                                          \
    {                                                                      \
        double da0[8], da1[8];                                             \
        _Pragma("unroll") for (int d = 0; d < 8; ++d) { da0[d]=0.0; da1[d]=0.0; } \
        _Pragma("unroll") for (int j = 0; j < 3; ++j) {                    \
            const float4 zvA = (j == 0) ? P##0 : (j == 1) ? P##1 : P##2;   \
            const float4 zvB = (j == 0) ? Q##0 : (j == 1) ? Q##1 : Q##2;   \
            const int fi = lane + 64 * j;                                  \
            const int sw = fi & 7;                                         \
            float fA[8], fB[8];                                            \
            _Pragma("unroll") for (int d = 0; d < 8; ++d) { fA[d]=0.f; fB[d]=0.f; } \
            _Pragma("unroll") for (int k = 0; k < 4; ++k) {                \
                const float aA = (k==0)?zvA.x:(k==1)?zvA.y:(k==2)?zvA.z:zvA.w; \
                const float aB = (k==0)?zvB.x:(k==1)?zvB.y:(k==2)?zvB.z:zvB.w; \
                const int a0 = 8 * fi + 2 * k;                             \
                const float4 wA = lds_w[a0 ^ sw];                          \
                const float4 wB = lds_w[(a0 + 1) ^ sw];                    \
                fA[0]=fmaf(aA,wA.x,fA[0]); fA[1]=fmaf(aA,wA.y,fA[1]);      \
                fA[2]=fmaf(aA,wA.z,fA[2]); fA[3]=fmaf(aA,wA.w,fA[3]);      \
                fA[4]=fmaf(aA,wB.x,fA[4]); fA[5]=fmaf(aA,wB.y,fA[5]);      \
                fA[6]=fmaf(aA,wB.z,fA[6]); fA[7]=fmaf(aA,wB.w,fA[7]);      \
                fB[0]=fmaf(aB,wA.x,fB[0]); fB[1]=fmaf(aB,wA.y,fB[1]);      \
                fB[2]=fmaf(aB,wA.z,fB[2]); fB[3]=fmaf(aB,wA.w,fB[3]);      \
                fB[4]=fmaf(aB,wB.x,fB[4]); fB[5]=fmaf(aB,wB.y,fB[5]);      \
                fB[6]=fmaf(aB,wB.z,fB[6]); fB[7]=fmaf(aB,wB.w,fB[7]);      \
            }                                                              \
            _Pragma("unroll") for (int d = 0; d < 8; ++d) {                \
                da0[d] += (double)fA[d];                                   \
                da1[d] += (double)fB[d];                                   \
            }                                                              \
        }                                                                  \
        REDUCE_TO_MINE(da0, ZCA)                                          \
        REDUCE_TO_MINE(da1, ZCB)                                          \
        ZCA += bc_mine;                                                    \
        ZCB += bc_mine;                                                    \
    }

// gumbel + argmax (f32 fast path, provably-safe f64 fallback) + qerr +
// pack -> wcodes[wid*8 + slot] (LDS; avoids runtime-indexed registers).
#define FIN_CODE(slot, ZC, UVF)                                            \
    {                                                                      \
        const float  uvf = (UVF) + 1e-10f;                                 \
        const float  gf  = -__logf(-__logf(uvf));                          \
        const double dist = fabs(ZC - (double)cb_mine);                    \
        double n = (double)gf - dist;                                      \
        const double n_orig = n;                                           \
        int li = lev;                                                      \
        _Pragma("unroll") for (int s = 8; s <= 32; s <<= 1) {              \
            const double on = __shfl_xor(n, s);                            \
            const int    ol = __shfl_xor(li, s);                           \
            const bool   t  = (on > n) || (on == n && ol < li);            \
            n = t ? on : n; li = t ? ol : li;                              \
        }                                                                  \
        const bool safe = (li == lev) || (n - n_orig > 1e-3);              \
        if (!__all((int)safe)) {                                           \
            const double uv = (double)(UVF) + 1e-10;                       \
            n = -log(-log(uv)) - dist;   /* exact verified f64 path */     \
            li = lev;                                                      \
            _Pragma("unroll") for (int s = 8; s <= 32; s <<= 1) {          \
                const double on = __shfl_xor(n, s);                        \
                const int    ol = __shfl_xor(li, s);                       \
                const bool   t  = (on > n) || (on == n && ol < li);        \
                n = t ? on : n; li = t ? ol : li;                          \
            }                                                              \
        }                                                                  \
        const float ci = cbl[dg * 8 + li];   /* same f32 value as verified */ \
        const double e = ZC - (double)ci;                                  \
        qa += e * e;                                                       \
        unsigned pk = (unsigned)li << (3 * dg);                            \
        pk += __shfl_xor(pk, 1);                                           \
        pk += __shfl_xor(pk, 2);                                           \
        pk += __shfl_xor(pk, 4);   /* full 24-bit pack in every lane */    \
        if (lane == 0) wcodes[wid * 8 + (slot)] = pk;                      \
    }

template <int USE_BPART>
__global__ __launch_bounds__(256, 5) void fsq_fused2(
    const float* __restrict__ z, const float* __restrict__ u,
    const float* __restrict__ Wc, const float* __restrict__ bc,
    const float* __restrict__ We, const float* __restrict__ be,
    const float* __restrict__ cb, float* __restrict__ zq,
    double* __restrict__ bpart)
{
    __shared__ float4   lds_w[1536];   // Wc, XOR-swizzled
    __shared__ float    cbl[64];
    __shared__ double   wsum[4];
    __shared__ unsigned wcodes[32];    // per-wave code parking (same-wave RW)

    const int lane = threadIdx.x & 63;
    const int wid  = threadIdx.x >> 6;
    const int dg   = lane & 7;
    const int lev  = lane >> 3;

    // ---- stage Wc (XOR-swizzled: idx ^ ((idx>>3)&7), involution) + cb ----
    {
        const float4* __restrict__ Wc4 = (const float4*)Wc;
        for (int t = threadIdx.x; t < 1536; t += 256)
            lds_w[t ^ ((t >> 3) & 7)] = Wc4[t];
        if (threadIdx.x < 64) cbl[threadIdx.x] = cb[threadIdx.x];
    }

    const float  cb_mine = cb[dg * 8 + lev];
    const double bc_mine = (double)bc[dg];
    const int b0 = lane & 1, b1 = (lane >> 1) & 1, b2 = (lane >> 2) & 1;

    const float4* __restrict__ z4 = (const float4*)z;

    const int wbase = (blockIdx.x * 4 + wid) * RPW;
    double qa = 0.0;

    __syncthreads();   // Wc image + cbl ready

    // ========== phase A: codes for 8 rows, 3-buffer rotation ==========
    // Buffers A,B,C cycle over pairs (A,B),(C,A),(B,C),(A,B); every load
    // is issued >= one FIN-pair + COMPRESS before its first use.
    float4 zA0, zA1, zA2, zB0, zB1, zB2, zC0, zC1, zC2;
    float  zAu, zBu, zCu, u0, u1;
    double zc0, zc1;

    LOADZ(zA, wbase + 0)
    LOADZ(zB, wbase + 1)
    LOADZ(zC, wbase + 2)                    // prefetch r2

    COMPRESS2(zA, zB, zc0, zc1)             // pair (r0, r1)
    u0 = zAu; u1 = zBu;
    LOADZ(zA, wbase + 3)                    // prefetch r3 (A dead)
    FIN_CODE(0, zc0, u0)
    FIN_CODE(1, zc1, u1)

    LOADZ(zB, wbase + 4)                    // prefetch r4 (B dead)
    COMPRESS2(zC, zA, zc0, zc1)             // pair (r2, r3)
    u0 = zCu; u1 = zAu;
    LOADZ(zC, wbase + 5)                    // prefetch r5 (C dead)
    FIN_CODE(2, zc0, u0)
    FIN_CODE(3, zc1, u1)

    LOADZ(zA, wbase + 6)                    // prefetch r6 (A dead)
    COMPRESS2(zB, zC, zc0, zc1)             // pair (r4, r5)
    u0 = zBu; u1 = zCu;
    LOADZ(zB, wbase + 7)                    // prefetch r7 (B dead)
    FIN_CODE(4, zc0, u0)
    FIN_CODE(5, zc1, u1)

    COMPRESS2(zA, zB, zc0, zc1)             // pair (r6, r7)
    u0 = zAu; u1 = zBu;
    FIN_CODE(6, zc0, u0)
    FIN_CODE(7, zc1, u1)

    // ========== phase B: expand the 8 rows, two 4-row groups ==========
    {
        const float4* __restrict__ We4 = (const float4*)We;
        const float4* __restrict__ be4 = (const float4*)be;
        float4* __restrict__ zq4 = (float4*)zq;
#pragma unroll 1
        for (int g = 0; g < 2; ++g) {
            const int r0 = wbase + 4 * g;
            const unsigned c0 = wcodes[wid * 8 + 4 * g + 0];
            const unsigned c1 = wcodes[wid * 8 + 4 * g + 1];
            const unsigned c2 = wcodes[wid * 8 + 4 * g + 2];
            const unsigned c3 = wcodes[wid * 8 + 4 * g + 3];
            float cd0[8], cd1[8], cd2[8], cd3[8];
#pragma unroll
            for (int d = 0; d < 8; ++d) {
                cd0[d] = cbl[d * 8 + ((c0 >> (3 * d)) & 7)];
                cd1[d] = cbl[d * 8 + ((c1 >> (3 * d)) & 7)];
                cd2[d] = cbl[d * 8 + ((c2 >> (3 * d)) & 7)];
                cd3[d] = cbl[d * 8 + ((c3 >> (3 * d)) & 7)];
            }
#pragma unroll
            for (int j = 0; j < 3; ++j) {
                const int fi = lane + 64 * j;
                const float4 bv = be4[fi];
                float4 o0 = bv, o1 = bv, o2 = bv, o3 = bv;
#pragma unroll
                for (int d = 0; d < 8; ++d) {
                    const float4 wv = We4[d * 192 + fi];
                    o0.x = fmaf(cd0[d], wv.x, o0.x); o0.y = fmaf(cd0[d], wv.y, o0.y);
                    o0.z = fmaf(cd0[d], wv.z, o0.z); o0.w = fmaf(cd0[d], wv.w, o0.w);
                    o1.x = fmaf(cd1[d], wv.x, o1.x); o1.y = fmaf(cd1[d], wv.y, o1.y);
                    o1.z = fmaf(cd1[d], wv.z, o1.z); o1.w = fmaf(cd1[d], wv.w, o1.w);
                    o2.x = fmaf(cd2[d], wv.x, o2.x); o2.y = fmaf(cd2[d], wv.y, o2.y);
                    o2.z = fmaf(cd2[d], wv.z, o2.z); o2.w = fmaf(cd2[d], wv.w, o2.w);
                    o3.x = fmaf(cd3[d], wv.x, o3.x); o3.y = fmaf(cd3[d], wv.y, o3.y);
                    o3.z = fmaf(cd3[d], wv.z, o3.z); o3.w = fmaf(cd3[d], wv.w, o3.w);
                }
                zq4[(size_t)r0 * 192 + fi]       = o0;
                zq4[(size_t)(r0 + 1) * 192 + fi] = o1;
                zq4[(size_t)(r0 + 2) * 192 + fi] = o2;
                zq4[(size_t)(r0 + 3) * 192 + fi] = o3;
            }
        }
    }

    // ---- quantization error: dg-reduce once per wave ----
    qa += __shfl_xor(qa, 1);
    qa += __shfl_xor(qa, 2);
    qa += __shfl_xor(qa, 4);
    if (USE_BPART) {
        if (lane == 0) wsum[wid] = qa;
        __syncthreads();
        if (threadIdx.x == 0)
            bpart[blockIdx.x] = (wsum[0] + wsum[1]) + (wsum[2] + wsum[3]);
    } else {
        if (lane == 0) atomicAdd(bpart, qa);
    }
}

// Deterministic fixed-order reduction of NBLK partials -> mean -> out.
__global__ __launch_bounds__(256) void fsq_tail_bpart(
    const double* __restrict__ bpart, float* __restrict__ out)
{
    __shared__ double s[256];
    const int t = threadIdx.x;
    double a = 0.0;
    for (int i = 0; i < NBLK / 256; ++i)          // fixed order
        a += bpart[t * (NBLK / 256) + i];
    s[t] = a;
    __syncthreads();
    for (int w = 128; w > 0; w >>= 1) {
        if (t < w) s[t] += s[t + w];
        __syncthreads();
    }
    if (t == 0) out[0] = (float)(s[0] * (1.0 / QCOUNT));
}

__global__ void fsq_tail_atomic(const double* __restrict__ qacc, float* __restrict__ out)
{
    out[0] = (float)(qacc[0] * (1.0 / QCOUNT));
}

extern "C" void kernel_launch(void* const* d_in, const int* in_sizes, int n_in,
                              void* d_out, int out_size, void* d_ws, size_t ws_size,
                              hipStream_t stream)
{
    const float* z  = (const float*)d_in[0];
    const float* u  = (const float*)d_in[1];
    const float* Wc = (const float*)d_in[2];
    const float* bc = (const float*)d_in[3];
    const float* We = (const float*)d_in[4];
    const float* be = (const float*)d_in[5];
    const float* cb = (const float*)d_in[6];
    // d_in[7] = codebook_mask: all levels == 8 -> mask all true, unused.

    float*  zq    = (float*)d_out;
    double* bpart = (double*)d_ws;

    if (ws_size >= (size_t)NBLK * sizeof(double)) {
        // no memset needed: every block overwrites its own slot
        fsq_fused2<1><<<dim3(NBLK), dim3(256), 0, stream>>>(z, u, Wc, bc, We, be, cb, zq, bpart);
        fsq_tail_bpart<<<dim3(1), dim3(256), 0, stream>>>(bpart, zq + (size_t)NROWS * CIN);
    } else {
        hipMemsetAsync(d_ws, 0, sizeof(double), stream);
        fsq_fused2<0><<<dim3(NBLK), dim3(256), 0, stream>>>(z, u, Wc, bc, We, be, cb, zq, bpart);
        fsq_tail_atomic<<<dim3(1), dim3(1), 0, stream>>>(bpart, zq + (size_t)NROWS * CIN);
    }
}

// Round 13
// 102.485 us; speedup vs baseline: 2.9952x; 2.9952x over previous
//
#include <hip/hip_runtime.h>
#include <math.h>

// Problem constants (match reference)
#define NROWS 65536          // B*S = 16*4096
#define CIN   768
#define QCOUNT 524288.0      // NROWS * DDIM
#define RPW   8              // rows per wave (phase A: 4 pairs)
#define NBLK  (NROWS / (4 * RPW))   // 2048 blocks of 4 waves

// R13 = R11 (fused temporal-phase, 101.5us, NO launch_bounds cap — R4/R6/R12
// proved any min-waves cap spills this kernel) + two genuine live-state cuts:
//   (1) 3-buffer z rotation: -12 VGPR vs 4-buffer ping-pong, same depth-1
//       prefetch cover, same row pairing/order. Goal: natural VGPR <= 102
//       -> 5 waves/SIMD without forcing the allocator.
//   (2) f32 fast-path argmax tournament: margin guard (1e-3 >> f32 path
//       error ~3e-5) proves winner identical to f64; sub-margin rows take
//       the exact f64 fallback. Saves 3 DS + f64 VALU per row + ~3 VGPR.
// Decision values bit-identical to the verified absmax-0.0 kernels.

// Distributing butterfly: reduce 8 per-lane f64 partials across 64 lanes,
// delivering zc[d] to lanes with (lane&7)==d. Fixed order, static selects.
#define REDUCE_TO_MINE(da, out)                                            \
    {                                                                      \
        double k0 = b0 ? da[1] : da[0], s0 = b0 ? da[0] : da[1];           \
        double k1 = b0 ? da[3] : da[2], s1 = b0 ? da[2] : da[3];           \
        double k2 = b0 ? da[5] : da[4], s2 = b0 ? da[4] : da[5];           \
        double k3 = b0 ? da[7] : da[6], s3 = b0 ? da[6] : da[7];           \
        k0 += __shfl_xor(s0, 1); k1 += __shfl_xor(s1, 1);                  \
        k2 += __shfl_xor(s2, 1); k3 += __shfl_xor(s3, 1);                  \
        double m0 = b1 ? k1 : k0, t0 = b1 ? k0 : k1;                       \
        double m1 = b1 ? k3 : k2, t1 = b1 ? k2 : k3;                       \
        m0 += __shfl_xor(t0, 2); m1 += __shfl_xor(t1, 2);                  \
        double r = b2 ? m1 : m0, tq = b2 ? m0 : m1;                        \
        r += __shfl_xor(tq, 4);                                            \
        r += __shfl_xor(r, 8);                                             \
        r += __shfl_xor(r, 16);                                            \
        r += __shfl_xor(r, 32);                                            \
        out = r;                                                           \
    }

// Load one row's z (3 coalesced float4) + u (coalesced permuted 256B)
#define LOADZ(B, row)                                                      \
    B##0 = z4[(size_t)(row) * 192 + lane];                                 \
    B##1 = z4[(size_t)(row) * 192 + lane + 64];                           \
    B##2 = z4[(size_t)(row) * 192 + lane + 128];                          \
    B##u = u[(size_t)(row) * 64 + dg * 8 + lev];

// compress TWO rows (buffers P,Q) sharing each Wc LDS read. Per-row
// arithmetic is the EXACT order of the verified absmax-0.0 kernel.
#define COMPRESS2(P, Q, ZCA, ZCB)                                          \
    {                                                                      \
        double da0[8], da1[8];                                             \
        _Pragma("unroll") for (int d = 0; d < 8; ++d) { da0[d]=0.0; da1[d]=0.0; } \
        _Pragma("unroll") for (int j = 0; j < 3; ++j) {                    \
            const float4 zvA = (j == 0) ? P##0 : (j == 1) ? P##1 : P##2;   \
            const float4 zvB = (j == 0) ? Q##0 : (j == 1) ? Q##1 : Q##2;   \
            const int fi = lane + 64 * j;                                  \
            const int sw = fi & 7;                                         \
            float fA[8], fB[8];                                            \
            _Pragma("unroll") for (int d = 0; d < 8; ++d) { fA[d]=0.f; fB[d]=0.f; } \
            _Pragma("unroll") for (int k = 0; k < 4; ++k) {                \
                const float aA = (k==0)?zvA.x:(k==1)?zvA.y:(k==2)?zvA.z:zvA.w; \
                const float aB = (k==0)?zvB.x:(k==1)?zvB.y:(k==2)?zvB.z:zvB.w; \
                const int a0 = 8 * fi + 2 * k;                             \
                const float4 wA = lds_w[a0 ^ sw];                          \
                const float4 wB = lds_w[(a0 + 1) ^ sw];                    \
                fA[0]=fmaf(aA,wA.x,fA[0]); fA[1]=fmaf(aA,wA.y,fA[1]);      \
                fA[2]=fmaf(aA,wA.z,fA[2]); fA[3]=fmaf(aA,wA.w,fA[3]);      \
                fA[4]=fmaf(aA,wB.x,fA[4]); fA[5]=fmaf(aA,wB.y,fA[5]);      \
                fA[6]=fmaf(aA,wB.z,fA[6]); fA[7]=fmaf(aA,wB.w,fA[7]);      \
                fB[0]=fmaf(aB,wA.x,fB[0]); fB[1]=fmaf(aB,wA.y,fB[1]);      \
                fB[2]=fmaf(aB,wA.z,fB[2]); fB[3]=fmaf(aB,wA.w,fB[3]);      \
                fB[4]=fmaf(aB,wB.x,fB[4]); fB[5]=fmaf(aB,wB.y,fB[5]);      \
                fB[6]=fmaf(aB,wB.z,fB[6]); fB[7]=fmaf(aB,wB.w,fB[7]);      \
            }                                                              \
            _Pragma("unroll") for (int d = 0; d < 8; ++d) {                \
                da0[d] += (double)fA[d];                                   \
                da1[d] += (double)fB[d];                                   \
            }                                                              \
        }                                                                  \
        REDUCE_TO_MINE(da0, ZCA)                                          \
        REDUCE_TO_MINE(da1, ZCB)                                          \
        ZCA += bc_mine;                                                    \
        ZCB += bc_mine;                                                    \
    }

// gumbel + argmax (f32 fast-path tournament, provably-safe f64 fallback)
// + qerr + pack -> wcodes[wid*8 + slot] (LDS parking).
// Fast-path error budget: |n_f32 - n_f64| <= ~3e-5 (hw __logf + f32 dist
// rounding + f32 subtract); safe margin 1e-3 >> 2x that -> winner provably
// identical to the f64 tournament. Sub-margin rows redo exact f64.
#define FIN_CODE(slot, ZC, UVF)                                            \
    {                                                                      \
        const float  uvf = (UVF) + 1e-10f;                                 \
        const float  gf  = -__logf(-__logf(uvf));                          \
        const double dist = fabs(ZC - (double)cb_mine);                    \
        const float  nf0 = gf - (float)dist;                               \
        float nf = nf0;                                                    \
        int   li = lev;                                                    \
        _Pragma("unroll") for (int s = 8; s <= 32; s <<= 1) {              \
            const float on = __shfl_xor(nf, s);                            \
            const int   ol = __shfl_xor(li, s);                            \
            const bool  t  = (on > nf) || (on == nf && ol < li);           \
            nf = t ? on : nf; li = t ? ol : li;                            \
        }                                                                  \
        const bool safe = (li == lev) || (nf - nf0 > 1e-3f);               \
        if (!__all((int)safe)) {                                           \
            const double uv = (double)(UVF) + 1e-10;                       \
            double n = -log(-log(uv)) - dist;  /* exact verified f64 path */ \
            li = lev;                                                      \
            _Pragma("unroll") for (int s = 8; s <= 32; s <<= 1) {          \
                const double on = __shfl_xor(n, s);                        \
                const int    ol = __shfl_xor(li, s);                       \
                const bool   t  = (on > n) || (on == n && ol < li);        \
                n = t ? on : n; li = t ? ol : li;                          \
            }                                                              \
        }                                                                  \
        const float ci = cbl[dg * 8 + li];   /* same f32 value as verified */ \
        const double e = ZC - (double)ci;                                  \
        qa += e * e;                                                       \
        unsigned pk = (unsigned)li << (3 * dg);                            \
        pk += __shfl_xor(pk, 1);                                           \
        pk += __shfl_xor(pk, 2);                                           \
        pk += __shfl_xor(pk, 4);   /* full 24-bit pack in every lane */    \
        if (lane == 0) wcodes[wid * 8 + (slot)] = pk;                      \
    }

template <int USE_BPART>
__global__ __launch_bounds__(256) void fsq_fused2(
    const float* __restrict__ z, const float* __restrict__ u,
    const float* __restrict__ Wc, const float* __restrict__ bc,
    const float* __restrict__ We, const float* __restrict__ be,
    const float* __restrict__ cb, float* __restrict__ zq,
    double* __restrict__ bpart)
{
    __shared__ float4   lds_w[1536];   // Wc, XOR-swizzled
    __shared__ float    cbl[64];
    __shared__ double   wsum[4];
    __shared__ unsigned wcodes[32];    // per-wave code parking (same-wave RW)

    const int lane = threadIdx.x & 63;
    const int wid  = threadIdx.x >> 6;
    const int dg   = lane & 7;
    const int lev  = lane >> 3;

    // ---- stage Wc (XOR-swizzled: idx ^ ((idx>>3)&7), involution) + cb ----
    {
        const float4* __restrict__ Wc4 = (const float4*)Wc;
        for (int t = threadIdx.x; t < 1536; t += 256)
            lds_w[t ^ ((t >> 3) & 7)] = Wc4[t];
        if (threadIdx.x < 64) cbl[threadIdx.x] = cb[threadIdx.x];
    }

    const float  cb_mine = cb[dg * 8 + lev];
    const double bc_mine = (double)bc[dg];
    const int b0 = lane & 1, b1 = (lane >> 1) & 1, b2 = (lane >> 2) & 1;

    const float4* __restrict__ z4 = (const float4*)z;

    const int wbase = (blockIdx.x * 4 + wid) * RPW;
    double qa = 0.0;

    __syncthreads();   // Wc image + cbl ready

    // ========== phase A: codes for 8 rows, 3-buffer rotation ==========
    // Buffers A,B,C cycle over pairs (A,B),(C,A),(B,C),(A,B); every load
    // is issued >= one FIN-pair + COMPRESS before its first use. Same row
    // pairing/order as the verified kernels.
    float4 zA0, zA1, zA2, zB0, zB1, zB2, zC0, zC1, zC2;
    float  zAu, zBu, zCu, u0, u1;
    double zc0, zc1;

    LOADZ(zA, wbase + 0)
    LOADZ(zB, wbase + 1)
    LOADZ(zC, wbase + 2)                    // prefetch r2

    COMPRESS2(zA, zB, zc0, zc1)             // pair (r0, r1)
    u0 = zAu; u1 = zBu;
    LOADZ(zA, wbase + 3)                    // prefetch r3 (A dead)
    FIN_CODE(0, zc0, u0)
    FIN_CODE(1, zc1, u1)

    LOADZ(zB, wbase + 4)                    // prefetch r4 (B dead)
    COMPRESS2(zC, zA, zc0, zc1)             // pair (r2, r3)
    u0 = zCu; u1 = zAu;
    LOADZ(zC, wbase + 5)                    // prefetch r5 (C dead)
    FIN_CODE(2, zc0, u0)
    FIN_CODE(3, zc1, u1)

    LOADZ(zA, wbase + 6)                    // prefetch r6 (A dead)
    COMPRESS2(zB, zC, zc0, zc1)             // pair (r4, r5)
    u0 = zBu; u1 = zCu;
    LOADZ(zB, wbase + 7)                    // prefetch r7 (B dead)
    FIN_CODE(4, zc0, u0)
    FIN_CODE(5, zc1, u1)

    COMPRESS2(zA, zB, zc0, zc1)             // pair (r6, r7)
    u0 = zAu; u1 = zBu;
    FIN_CODE(6, zc0, u0)
    FIN_CODE(7, zc1, u1)

    // ========== phase B: expand the 8 rows, two 4-row groups ==========
    {
        const float4* __restrict__ We4 = (const float4*)We;
        const float4* __restrict__ be4 = (const float4*)be;
        float4* __restrict__ zq4 = (float4*)zq;
#pragma unroll 1
        for (int g = 0; g < 2; ++g) {
            const int r0 = wbase + 4 * g;
            const unsigned c0 = wcodes[wid * 8 + 4 * g + 0];
            const unsigned c1 = wcodes[wid * 8 + 4 * g + 1];
            const unsigned c2 = wcodes[wid * 8 + 4 * g + 2];
            const unsigned c3 = wcodes[wid * 8 + 4 * g + 3];
            float cd0[8], cd1[8], cd2[8], cd3[8];
#pragma unroll
            for (int d = 0; d < 8; ++d) {
                cd0[d] = cbl[d * 8 + ((c0 >> (3 * d)) & 7)];
                cd1[d] = cbl[d * 8 + ((c1 >> (3 * d)) & 7)];
                cd2[d] = cbl[d * 8 + ((c2 >> (3 * d)) & 7)];
                cd3[d] = cbl[d * 8 + ((c3 >> (3 * d)) & 7)];
            }
#pragma unroll
            for (int j = 0; j < 3; ++j) {
                const int fi = lane + 64 * j;
                const float4 bv = be4[fi];
                float4 o0 = bv, o1 = bv, o2 = bv, o3 = bv;
#pragma unroll
                for (int d = 0; d < 8; ++d) {
                    const float4 wv = We4[d * 192 + fi];
                    o0.x = fmaf(cd0[d], wv.x, o0.x); o0.y = fmaf(cd0[d], wv.y, o0.y);
                    o0.z = fmaf(cd0[d], wv.z, o0.z); o0.w = fmaf(cd0[d], wv.w, o0.w);
                    o1.x = fmaf(cd1[d], wv.x, o1.x); o1.y = fmaf(cd1[d], wv.y, o1.y);
                    o1.z = fmaf(cd1[d], wv.z, o1.z); o1.w = fmaf(cd1[d], wv.w, o1.w);
                    o2.x = fmaf(cd2[d], wv.x, o2.x); o2.y = fmaf(cd2[d], wv.y, o2.y);
                    o2.z = fmaf(cd2[d], wv.z, o2.z); o2.w = fmaf(cd2[d], wv.w, o2.w);
                    o3.x = fmaf(cd3[d], wv.x, o3.x); o3.y = fmaf(cd3[d], wv.y, o3.y);
                    o3.z = fmaf(cd3[d], wv.z, o3.z); o3.w = fmaf(cd3[d], wv.w, o3.w);
                }
                zq4[(size_t)r0 * 192 + fi]       = o0;
                zq4[(size_t)(r0 + 1) * 192 + fi] = o1;
                zq4[(size_t)(r0 + 2) * 192 + fi] = o2;
                zq4[(size_t)(r0 + 3) * 192 + fi] = o3;
            }
        }
    }

    // ---- quantization error: dg-reduce once per wave ----
    qa += __shfl_xor(qa, 1);
    qa += __shfl_xor(qa, 2);
    qa += __shfl_xor(qa, 4);
    if (USE_BPART) {
        if (lane == 0) wsum[wid] = qa;
        __syncthreads();
        if (threadIdx.x == 0)
            bpart[blockIdx.x] = (wsum[0] + wsum[1]) + (wsum[2] + wsum[3]);
    } else {
        if (lane == 0) atomicAdd(bpart, qa);
    }
}

// Deterministic fixed-order reduction of NBLK partials -> mean -> out.
__global__ __launch_bounds__(256) void fsq_tail_bpart(
    const double* __restrict__ bpart, float* __restrict__ out)
{
    __shared__ double s[256];
    const int t = threadIdx.x;
    double a = 0.0;
    for (int i = 0; i < NBLK / 256; ++i)          // fixed order
        a += bpart[t * (NBLK / 256) + i];
    s[t] = a;
    __syncthreads();
    for (int w = 128; w > 0; w >>= 1) {
        if (t < w) s[t] += s[t + w];
        __syncthreads();
    }
    if (t == 0) out[0] = (float)(s[0] * (1.0 / QCOUNT));
}

__global__ void fsq_tail_atomic(const double* __restrict__ qacc, float* __restrict__ out)
{
    out[0] = (float)(qacc[0] * (1.0 / QCOUNT));
}

extern "C" void kernel_launch(void* const* d_in, const int* in_sizes, int n_in,
                              void* d_out, int out_size, void* d_ws, size_t ws_size,
                              hipStream_t stream)
{
    const float* z  = (const float*)d_in[0];
    const float* u  = (const float*)d_in[1];
    const float* Wc = (const float*)d_in[2];
    const float* bc = (const float*)d_in[3];
    const float* We = (const float*)d_in[4];
    const float* be = (const float*)d_in[5];
    const float* cb = (const float*)d_in[6];
    // d_in[7] = codebook_mask: all levels == 8 -> mask all true, unused.

    float*  zq    = (float*)d_out;
    double* bpart = (double*)d_ws;

    if (ws_size >= (size_t)NBLK * sizeof(double)) {
        // no memset needed: every block overwrites its own slot
        fsq_fused2<1><<<dim3(NBLK), dim3(256), 0, stream>>>(z, u, Wc, bc, We, be, cb, zq, bpart);
        fsq_tail_bpart<<<dim3(1), dim3(256), 0, stream>>>(bpart, zq + (size_t)NROWS * CIN);
    } else {
        hipMemsetAsync(d_ws, 0, sizeof(double), stream);
        fsq_fused2<0><<<dim3(NBLK), dim3(256), 0, stream>>>(z, u, Wc, bc, We, be, cb, zq, bpart);
        fsq_tail_atomic<<<dim3(1), dim3(1), 0, stream>>>(bpart, zq + (size_t)NROWS * CIN);
    }
}

// Round 14
// 100.351 us; speedup vs baseline: 3.0589x; 1.0213x over previous
//
#include <hip/hip_runtime.h>
#include <math.h>

// Problem constants (match reference)
#define NROWS 65536          // B*S = 16*4096
#define CIN   768
#define QCOUNT 524288.0      // NROWS * DDIM
#define RPW   8              // rows per wave (phase A: 4 pairs, ping-pong prefetch)
#define NBLK  (NROWS / (4 * RPW))   // 2048 blocks of 4 waves

// R14 = R11 (fused temporal-phase, 101.5us best; NO launch_bounds cap) +
// shuffle offload: xor1/xor2 -> DPP quad_perm, xor8 -> DPP row_ror:8
// (exact lane^8 within 16-lane rows), code-pack -> __ballot + SALU
// bit-scatter. Same lane data movement, moved from DS pipe (~25cyc
// ds_swizzle) to VALU DPP (~2cyc) / SALU. xor4/16/32 remain ds_swizzle.
// Decision values bit-identical to the verified absmax-0.0 kernels.
// R4/R6/R12/R13 lesson: occupancy is pinned (~4 waves/SIMD); this attacks
// the per-row serial shuffle chain instead.

// ---- DPP lane-permute helpers (compile-time ctrl) ----
// quad_perm[1,0,3,2]=0xB1 (lane^1), quad_perm[2,3,0,1]=0x4E (lane^2),
// row_ror:8=0x128 (lane^8 within 16-lane row).
template <int C>
__device__ __forceinline__ float dppf(float x) {
    return __int_as_float(__builtin_amdgcn_update_dpp(
        0, __float_as_int(x), C, 0xF, 0xF, true));
}
template <int C>
__device__ __forceinline__ int dppi(int x) {
    return __builtin_amdgcn_update_dpp(0, x, C, 0xF, 0xF, true);
}
template <int C>
__device__ __forceinline__ double dppd(double x) {
    const long long xi = __double_as_longlong(x);
    const int lo = __builtin_amdgcn_update_dpp(0, (int)xi, C, 0xF, 0xF, true);
    const int hi = __builtin_amdgcn_update_dpp(0, (int)(xi >> 32), C, 0xF, 0xF, true);
    return __longlong_as_double((long long)(unsigned)lo | ((long long)hi << 32));
}
#define DXOR1 0xB1
#define DXOR2 0x4E
#define DXOR8 0x128

// Distributing butterfly: reduce 8 per-lane f64 partials across 64 lanes,
// delivering zc[d] to lanes with (lane&7)==d. Fixed order, static selects.
// xor1/xor2/xor8 exchanges via DPP (exact same lane pairing as shfl_xor).
#define REDUCE_TO_MINE(da, out)                                            \
    {                                                                      \
        double k0 = b0 ? da[1] : da[0], s0 = b0 ? da[0] : da[1];           \
        double k1 = b0 ? da[3] : da[2], s1 = b0 ? da[2] : da[3];           \
        double k2 = b0 ? da[5] : da[4], s2 = b0 ? da[4] : da[5];           \
        double k3 = b0 ? da[7] : da[6], s3 = b0 ? da[6] : da[7];           \
        k0 += dppd<DXOR1>(s0); k1 += dppd<DXOR1>(s1);                      \
        k2 += dppd<DXOR1>(s2); k3 += dppd<DXOR1>(s3);                      \
        double m0 = b1 ? k1 : k0, t0 = b1 ? k0 : k1;                       \
        double m1 = b1 ? k3 : k2, t1 = b1 ? k2 : k3;                       \
        m0 += dppd<DXOR2>(t0); m1 += dppd<DXOR2>(t1);                      \
        double r = b2 ? m1 : m0, tq = b2 ? m0 : m1;                        \
        r += __shfl_xor(tq, 4);                                            \
        r += dppd<DXOR8>(r);                                               \
        r += __shfl_xor(r, 16);                                            \
        r += __shfl_xor(r, 32);                                            \
        out = r;                                                           \
    }

// Load one row's z (3 coalesced float4) + u (coalesced permuted 256B)
#define LOADZ(B, row)                                                      \
    B##0 = z4[(size_t)(row) * 192 + lane];                                 \
    B##1 = z4[(size_t)(row) * 192 + lane + 64];                           \
    B##2 = z4[(size_t)(row) * 192 + lane + 128];                          \
    B##u = u[(size_t)(row) * 64 + dg * 8 + lev];

// compress TWO rows (buffers P,Q) sharing each Wc LDS read. Per-row
// arithmetic is the EXACT order of the verified absmax-0.0 kernel.
#define COMPRESS2(P, Q, ZCA, ZCB)                                          \
    {                                                                      \
        double da0[8], da1[8];                                             \
        _Pragma("unroll") for (int d = 0; d < 8; ++d) { da0[d]=0.0; da1[d]=0.0; } \
        _Pragma("unroll") for (int j = 0; j < 3; ++j) {                    \
            const float4 zvA = (j == 0) ? P##0 : (j == 1) ? P##1 : P##2;   \
            const float4 zvB = (j == 0) ? Q##0 : (j == 1) ? Q##1 : Q##2;   \
            const int fi = lane + 64 * j;                                  \
            const int sw = fi & 7;                                         \
            float fA[8], fB[8];                                            \
            _Pragma("unroll") for (int d = 0; d < 8; ++d) { fA[d]=0.f; fB[d]=0.f; } \
            _Pragma("unroll") for (int k = 0; k < 4; ++k) {                \
                const float aA = (k==0)?zvA.x:(k==1)?zvA.y:(k==2)?zvA.z:zvA.w; \
                const float aB = (k==0)?zvB.x:(k==1)?zvB.y:(k==2)?zvB.z:zvB.w; \
                const int a0 = 8 * fi + 2 * k;                             \
                const float4 wA = lds_w[a0 ^ sw];                          \
                const float4 wB = lds_w[(a0 + 1) ^ sw];                    \
                fA[0]=fmaf(aA,wA.x,fA[0]); fA[1]=fmaf(aA,wA.y,fA[1]);      \
                fA[2]=fmaf(aA,wA.z,fA[2]); fA[3]=fmaf(aA,wA.w,fA[3]);      \
                fA[4]=fmaf(aA,wB.x,fA[4]); fA[5]=fmaf(aA,wB.y,fA[5]);      \
                fA[6]=fmaf(aA,wB.z,fA[6]); fA[7]=fmaf(aA,wB.w,fA[7]);      \
                fB[0]=fmaf(aB,wA.x,fB[0]); fB[1]=fmaf(aB,wA.y,fB[1]);      \
                fB[2]=fmaf(aB,wA.z,fB[2]); fB[3]=fmaf(aB,wA.w,fB[3]);      \
                fB[4]=fmaf(aB,wB.x,fB[4]); fB[5]=fmaf(aB,wB.y,fB[5]);      \
                fB[6]=fmaf(aB,wB.z,fB[6]); fB[7]=fmaf(aB,wB.w,fB[7]);      \
            }                                                              \
            _Pragma("unroll") for (int d = 0; d < 8; ++d) {                \
                da0[d] += (double)fA[d];                                   \
                da1[d] += (double)fB[d];                                   \
            }                                                              \
        }                                                                  \
        REDUCE_TO_MINE(da0, ZCA)                                          \
        REDUCE_TO_MINE(da1, ZCB)                                          \
        ZCA += bc_mine;                                                    \
        ZCB += bc_mine;                                                    \
    }

// gumbel + argmax (f32 fast-path tournament w/ DPP xor8, provably-safe f64
// fallback) + qerr + ballot-pack -> wcodes[wid*8 + slot] (LDS parking).
// Fast-path error <= ~3e-5 << 1e-3 safety margin -> winner provably
// identical to f64 tournament; sub-margin rows redo exact f64.
#define FIN_CODE(slot, ZC, UVF)                                            \
    {                                                                      \
        const float  uvf = (UVF) + 1e-10f;                                 \
        const float  gf  = -__logf(-__logf(uvf));                          \
        const double dist = fabs(ZC - (double)cb_mine);                    \
        const float  nf0 = gf - (float)dist;                               \
        float nf = nf0;                                                    \
        int   li = lev;                                                    \
        {                                                                  \
            const float on = dppf<DXOR8>(nf);                              \
            const int   ol = dppi<DXOR8>(li);                              \
            const bool  t  = (on > nf) || (on == nf && ol < li);           \
            nf = t ? on : nf; li = t ? ol : li;                            \
        }                                                                  \
        _Pragma("unroll") for (int s = 16; s <= 32; s <<= 1) {             \
            const float on = __shfl_xor(nf, s);                            \
            const int   ol = __shfl_xor(li, s);                            \
            const bool  t  = (on > nf) || (on == nf && ol < li);           \
            nf = t ? on : nf; li = t ? ol : li;                            \
        }                                                                  \
        const bool safe = (li == lev) || (nf - nf0 > 1e-3f);               \
        if (!__all((int)safe)) {                                           \
            const double uv = (double)(UVF) + 1e-10;                       \
            double n = -log(-log(uv)) - dist;  /* exact verified f64 path */ \
            li = lev;                                                      \
            _Pragma("unroll") for (int s = 8; s <= 32; s <<= 1) {          \
                const double on = __shfl_xor(n, s);                        \
                const int    ol = __shfl_xor(li, s);                       \
                const bool   t  = (on > n) || (on == n && ol < li);        \
                n = t ? on : n; li = t ? ol : li;                          \
            }                                                              \
        }                                                                  \
        const float ci = cbl[dg * 8 + li];   /* same f32 value as verified */ \
        const double e = ZC - (double)ci;                                  \
        qa += e * e;                                                       \
        /* pack via 3 ballots + uniform SALU bit-scatter (zero DS ops): */ \
        const unsigned long long mb0 = __ballot(li & 1);                   \
        const unsigned long long mb1 = __ballot(li & 2);                   \
        const unsigned long long mb2 = __ballot(li & 4);                   \
        unsigned pk = 0;                                                   \
        _Pragma("unroll") for (int d2 = 0; d2 < 8; ++d2) {                 \
            const unsigned bits = (unsigned)((mb0 >> d2) & 1ull)           \
                                | ((unsigned)((mb1 >> d2) & 1ull) << 1)    \
                                | ((unsigned)((mb2 >> d2) & 1ull) << 2);   \
            pk |= bits << (3 * d2);                                        \
        }                                                                  \
        if (lane == 0) wcodes[wid * 8 + (slot)] = pk;                      \
    }

template <int USE_BPART>
__global__ __launch_bounds__(256) void fsq_fused2(
    const float* __restrict__ z, const float* __restrict__ u,
    const float* __restrict__ Wc, const float* __restrict__ bc,
    const float* __restrict__ We, const float* __restrict__ be,
    const float* __restrict__ cb, float* __restrict__ zq,
    double* __restrict__ bpart)
{
    __shared__ float4   lds_w[1536];   // Wc, XOR-swizzled
    __shared__ float    cbl[64];
    __shared__ double   wsum[4];
    __shared__ unsigned wcodes[32];    // per-wave code parking (same-wave RW)

    const int lane = threadIdx.x & 63;
    const int wid  = threadIdx.x >> 6;
    const int dg   = lane & 7;
    const int lev  = lane >> 3;

    // ---- stage Wc (XOR-swizzled: idx ^ ((idx>>3)&7), involution) + cb ----
    {
        const float4* __restrict__ Wc4 = (const float4*)Wc;
        for (int t = threadIdx.x; t < 1536; t += 256)
            lds_w[t ^ ((t >> 3) & 7)] = Wc4[t];
        if (threadIdx.x < 64) cbl[threadIdx.x] = cb[threadIdx.x];
    }

    const float  cb_mine = cb[dg * 8 + lev];
    const double bc_mine = (double)bc[dg];
    const int b0 = lane & 1, b1 = (lane >> 1) & 1, b2 = (lane >> 2) & 1;

    const float4* __restrict__ z4 = (const float4*)z;

    const int wbase = (blockIdx.x * 4 + wid) * RPW;
    double qa = 0.0;

    __syncthreads();   // Wc image + cbl ready

    // ========== phase A: codes for all 8 rows (ping-pong pair pipeline) ==========
    float4 zA0, zA1, zA2, zB0, zB1, zB2, zC0, zC1, zC2, zD0, zD1, zD2;
    float  zAu, zBu, zCu, zDu;
    double zc0, zc1;

    LOADZ(zA, wbase + 0)
    LOADZ(zB, wbase + 1)
#pragma unroll 1
    for (int itp = 0; itp < RPW / 4; ++itp) {     // 2 iterations, 2 pairs each
        const int r0 = wbase + 4 * itp;
        const int s0 = 4 * itp;
        LOADZ(zC, r0 + 2)                          // prefetch pair k+1
        LOADZ(zD, r0 + 3)
        COMPRESS2(zA, zB, zc0, zc1)
        FIN_CODE(s0, zc0, zAu)
        FIN_CODE(s0 + 1, zc1, zBu)
        if (itp != RPW / 4 - 1) {                  // prefetch pair k+2
            LOADZ(zA, r0 + 4)
            LOADZ(zB, r0 + 5)
        }
        COMPRESS2(zC, zD, zc0, zc1)
        FIN_CODE(s0 + 2, zc0, zCu)
        FIN_CODE(s0 + 3, zc1, zDu)
    }

    // ========== phase B: expand the 8 rows, two 4-row groups ==========
    {
        const float4* __restrict__ We4 = (const float4*)We;
        const float4* __restrict__ be4 = (const float4*)be;
        float4* __restrict__ zq4 = (float4*)zq;
#pragma unroll 1
        for (int g = 0; g < 2; ++g) {
            const int r0 = wbase + 4 * g;
            const unsigned c0 = wcodes[wid * 8 + 4 * g + 0];
            const unsigned c1 = wcodes[wid * 8 + 4 * g + 1];
            const unsigned c2 = wcodes[wid * 8 + 4 * g + 2];
            const unsigned c3 = wcodes[wid * 8 + 4 * g + 3];
            float cd0[8], cd1[8], cd2[8], cd3[8];
#pragma unroll
            for (int d = 0; d < 8; ++d) {
                cd0[d] = cbl[d * 8 + ((c0 >> (3 * d)) & 7)];
                cd1[d] = cbl[d * 8 + ((c1 >> (3 * d)) & 7)];
                cd2[d] = cbl[d * 8 + ((c2 >> (3 * d)) & 7)];
                cd3[d] = cbl[d * 8 + ((c3 >> (3 * d)) & 7)];
            }
#pragma unroll
            for (int j = 0; j < 3; ++j) {
                const int fi = lane + 64 * j;
                const float4 bv = be4[fi];
                float4 o0 = bv, o1 = bv, o2 = bv, o3 = bv;
#pragma unroll
                for (int d = 0; d < 8; ++d) {
                    const float4 wv = We4[d * 192 + fi];
                    o0.x = fmaf(cd0[d], wv.x, o0.x); o0.y = fmaf(cd0[d], wv.y, o0.y);
                    o0.z = fmaf(cd0[d], wv.z, o0.z); o0.w = fmaf(cd0[d], wv.w, o0.w);
                    o1.x = fmaf(cd1[d], wv.x, o1.x); o1.y = fmaf(cd1[d], wv.y, o1.y);
                    o1.z = fmaf(cd1[d], wv.z, o1.z); o1.w = fmaf(cd1[d], wv.w, o1.w);
                    o2.x = fmaf(cd2[d], wv.x, o2.x); o2.y = fmaf(cd2[d], wv.y, o2.y);
                    o2.z = fmaf(cd2[d], wv.z, o2.z); o2.w = fmaf(cd2[d], wv.w, o2.w);
                    o3.x = fmaf(cd3[d], wv.x, o3.x); o3.y = fmaf(cd3[d], wv.y, o3.y);
                    o3.z = fmaf(cd3[d], wv.z, o3.z); o3.w = fmaf(cd3[d], wv.w, o3.w);
                }
                zq4[(size_t)r0 * 192 + fi]       = o0;
                zq4[(size_t)(r0 + 1) * 192 + fi] = o1;
                zq4[(size_t)(r0 + 2) * 192 + fi] = o2;
                zq4[(size_t)(r0 + 3) * 192 + fi] = o3;
            }
        }
    }

    // ---- quantization error: dg-reduce once per wave (DPP xor1/xor2) ----
    qa += dppd<DXOR1>(qa);
    qa += dppd<DXOR2>(qa);
    qa += __shfl_xor(qa, 4);
    if (USE_BPART) {
        if (lane == 0) wsum[wid] = qa;
        __syncthreads();
        if (threadIdx.x == 0)
            bpart[blockIdx.x] = (wsum[0] + wsum[1]) + (wsum[2] + wsum[3]);
    } else {
        if (lane == 0) atomicAdd(bpart, qa);
    }
}

// Deterministic fixed-order reduction of NBLK partials -> mean -> out.
__global__ __launch_bounds__(256) void fsq_tail_bpart(
    const double* __restrict__ bpart, float* __restrict__ out)
{
    __shared__ double s[256];
    const int t = threadIdx.x;
    double a = 0.0;
    for (int i = 0; i < NBLK / 256; ++i)          // fixed order
        a += bpart[t * (NBLK / 256) + i];
    s[t] = a;
    __syncthreads();
    for (int w = 128; w > 0; w >>= 1) {
        if (t < w) s[t] += s[t + w];
        __syncthreads();
    }
    if (t == 0) out[0] = (float)(s[0] * (1.0 / QCOUNT));
}

__global__ void fsq_tail_atomic(const double* __restrict__ qacc, float* __restrict__ out)
{
    out[0] = (float)(qacc[0] * (1.0 / QCOUNT));
}

extern "C" void kernel_launch(void* const* d_in, const int* in_sizes, int n_in,
                              void* d_out, int out_size, void* d_ws, size_t ws_size,
                              hipStream_t stream)
{
    const float* z  = (const float*)d_in[0];
    const float* u  = (const float*)d_in[1];
    const float* Wc = (const float*)d_in[2];
    const float* bc = (const float*)d_in[3];
    const float* We = (const float*)d_in[4];
    const float* be = (const float*)d_in[5];
    const float* cb = (const float*)d_in[6];
    // d_in[7] = codebook_mask: all levels == 8 -> mask all true, unused.

    float*  zq    = (float*)d_out;
    double* bpart = (double*)d_ws;

    if (ws_size >= (size_t)NBLK * sizeof(double)) {
        // no memset needed: every block overwrites its own slot
        fsq_fused2<1><<<dim3(NBLK), dim3(256), 0, stream>>>(z, u, Wc, bc, We, be, cb, zq, bpart);
        fsq_tail_bpart<<<dim3(1), dim3(256), 0, stream>>>(bpart, zq + (size_t)NROWS * CIN);
    } else {
        hipMemsetAsync(d_ws, 0, sizeof(double), stream);
        fsq_fused2<0><<<dim3(NBLK), dim3(256), 0, stream>>>(z, u, Wc, bc, We, be, cb, zq, bpart);
        fsq_tail_atomic<<<dim3(1), dim3(1), 0, stream>>>(bpart, zq + (size_t)NROWS * CIN);
    }
}